// Round 3
// baseline (959.121 us; speedup 1.0000x reference)
//
#include <hip/hip_runtime.h>

typedef unsigned short u16;
typedef __attribute__((ext_vector_type(8))) short bf16x8;
typedef __attribute__((ext_vector_type(4))) float f32x4;

#define SEQS 64
#define LSEQ 128
#define MROWS 8192
#define DM 768
#define DI 1536
#define NSTATE 16
#define DTR 48
#define XDB 80   // DTR + 2*NSTATE
#define CHUNK 4
#define CLEN 32  // LSEQ / CHUNK

// ---------- helpers ----------
__device__ __forceinline__ u16 f2b(float f) {
    unsigned int x = __builtin_bit_cast(unsigned int, f);
    unsigned int r = (x + 0x7fffu + ((x >> 16) & 1u)) >> 16;
    return (u16)r;
}
__device__ __forceinline__ float b2f(u16 v) {
    return __builtin_bit_cast(float, (unsigned int)v << 16);
}
__device__ __forceinline__ float softplusf(float x) {
    return x > 20.f ? x : log1pf(__expf(x));
}

// ---------- diagnostic ----------
__global__ void diag_kernel(float* __restrict__ out, int n, float v) {
    int i = blockIdx.x * 256 + threadIdx.x;
    int s = gridDim.x * 256;
    for (; i < n; i += s) out[i] = v;
}

// ---------- elementwise kernels ----------
__global__ void cvt_kernel(const float* __restrict__ src, u16* __restrict__ dst, int n) {
    int i = blockIdx.x * 256 + threadIdx.x;
    int stride = gridDim.x * 256;
    for (; i < n; i += stride) dst[i] = f2b(src[i]);
}

__global__ void patchify_kernel(const float* __restrict__ x, u16* __restrict__ o) {
    int idx = blockIdx.x * 256 + threadIdx.x;
    if (idx >= MROWS * DM) return;
    int col = idx % DM;
    int row = idx / DM;
    int t = row & 127, bb = row >> 7;
    int b = bb >> 4, h1 = (bb >> 2) & 3, h2 = bb & 3;
    int f = col >> 8, rem = col & 255, pi = rem >> 4, pj = rem & 15;
    size_t src = (size_t)(b * 128 + t) * 3 * 4096 + (size_t)f * 4096 + (h1 * 16 + pi) * 64 + h2 * 16 + pj;
    o[idx] = f2b(x[src]);
}

__global__ void unpatchify_kernel(const float* __restrict__ yo, float* __restrict__ out) {
    int idx = blockIdx.x * 256 + threadIdx.x;
    if (idx >= MROWS * DM) return;
    int w = idx & 63;
    int h = (idx >> 6) & 63;
    int f = (idx >> 12) % 3;
    int t = (idx / 12288) & 127;
    int b = idx / 1572864;
    int h1 = h >> 4, pi = h & 15, h2 = w >> 4, pj = w & 15;
    int row = ((b * 16 + h1 * 4 + h2) << 7) + t;
    int col = f * 256 + pi * 16 + pj;
    out[idx] = yo[(size_t)row * DM + col];
}

__global__ __launch_bounds__(256) void ln_kernel(const float* __restrict__ h, const float* __restrict__ w,
                                                 const float* __restrict__ b, u16* __restrict__ o) {
    __shared__ float red[8];
    int row = blockIdx.x, t = threadIdx.x;
    const float* hr = h + (size_t)row * DM;
    float v0 = hr[t], v1 = hr[t + 256], v2 = hr[t + 512];
    float s = v0 + v1 + v2;
    for (int off = 32; off; off >>= 1) s += __shfl_down(s, off);
    if ((t & 63) == 0) red[t >> 6] = s;
    __syncthreads();
    float mu = (red[0] + red[1] + red[2] + red[3]) * (1.f / 768.f);
    float d0 = v0 - mu, d1 = v1 - mu, d2 = v2 - mu;
    float q = d0 * d0 + d1 * d1 + d2 * d2;
    for (int off = 32; off; off >>= 1) q += __shfl_down(q, off);
    __syncthreads();
    if ((t & 63) == 0) red[4 + (t >> 6)] = q;
    __syncthreads();
    float var = (red[4] + red[5] + red[6] + red[7]) * (1.f / 768.f);
    float inv = rsqrtf(var + 1e-5f);
    u16* orow = o + (size_t)row * DM;
    orow[t]       = f2b(d0 * inv * w[t] + b[t]);
    orow[t + 256] = f2b(d1 * inv * w[t + 256] + b[t + 256]);
    orow[t + 512] = f2b(d2 * inv * w[t + 512] + b[t + 512]);
}

// conv over uraw (f32, row stride DI), causal depthwise 4-tap, + SiLU -> bf16
__global__ void conv_silu_kernel(const float* __restrict__ uraw, const float* __restrict__ cw,
                                 const float* __restrict__ cb, u16* __restrict__ u) {
    int idx = blockIdx.x * 256 + threadIdx.x;
    if (idx >= MROWS * DI) return;
    int c = idx % DI;
    int r = idx / DI;
    int t = r & 127;
    const float* base = uraw + (size_t)r * DI + c;
    float acc = cb[c];
#pragma unroll
    for (int k = 0; k < 4; k++) {
        int tt = t - 3 + k;
        if (tt >= 0) acc += base[(size_t)(k - 3) * DI] * cw[c * 4 + k];
    }
    float sv = acc / (1.f + __expf(-acc));
    u[idx] = f2b(sv);
}

// ---------- chunk-parallel selective scan ----------
// pass 1: per (d, seq, chunk): local scan from h=0 -> h_fin (bf16), chunk dt-sum T (bf16)
__global__ __launch_bounds__(256) void scan1_kernel(const u16* __restrict__ u, const float* __restrict__ delta,
                                                    const float* __restrict__ xdbl, const float* __restrict__ Alog,
                                                    u16* __restrict__ hfin, u16* __restrict__ Tsum) {
    __shared__ float bs[CLEN * 16];
    int d = blockIdx.x * 256 + threadIdx.x;
    int seq = blockIdx.y, c = blockIdx.z;
    const float* xb = xdbl + ((size_t)seq * LSEQ + c * CLEN) * XDB;
    for (int i = threadIdx.x; i < CLEN * 16; i += 256)
        bs[i] = xb[(i >> 4) * XDB + DTR + (i & 15)];
    __syncthreads();
    float an[NSTATE];
#pragma unroll
    for (int n4 = 0; n4 < 4; n4++) {
        float4 al = *(const float4*)(Alog + (size_t)d * NSTATE + n4 * 4);
        an[n4 * 4 + 0] = -__expf(al.x); an[n4 * 4 + 1] = -__expf(al.y);
        an[n4 * 4 + 2] = -__expf(al.z); an[n4 * 4 + 3] = -__expf(al.w);
    }
    float hs[NSTATE];
#pragma unroll
    for (int n = 0; n < NSTATE; n++) hs[n] = 0.f;
    float S = 0.f;
    size_t base = ((size_t)seq * LSEQ + c * CLEN) * DI + d;
    for (int t = 0; t < CLEN; t++) {
        size_t off = base + (size_t)t * DI;
        float dt = delta[off];
        float uv = b2f(u[off]);
        S += dt;
        float du = dt * uv;
        const float* Bp = bs + t * 16;
#pragma unroll
        for (int n = 0; n < NSTATE; n++)
            hs[n] = __expf(dt * an[n]) * hs[n] + du * Bp[n];
    }
    size_t hb = (size_t)(seq * CHUNK + c) * NSTATE * DI + d;
#pragma unroll
    for (int n = 0; n < NSTATE; n++) hfin[hb + (size_t)n * DI] = f2b(hs[n]);
    Tsum[(size_t)(seq * CHUNK + c) * DI + d] = f2b(S);
}

// pass 2: reconstruct h_in from prior chunks' (h_fin, T), rerun scan, fuse D-skip + SiLU gate
__global__ __launch_bounds__(256) void scan2_kernel(const u16* __restrict__ u, const float* __restrict__ delta,
                                                    const float* __restrict__ xdbl, const float* __restrict__ Alog,
                                                    const u16* __restrict__ hfin, const u16* __restrict__ Tsum,
                                                    const u16* __restrict__ zb, const float* __restrict__ Dk,
                                                    u16* __restrict__ yb) {
    __shared__ float bs[CLEN * 32];
    int d = blockIdx.x * 256 + threadIdx.x;
    int seq = blockIdx.y, c = blockIdx.z;
    const float* xb = xdbl + ((size_t)seq * LSEQ + c * CLEN) * XDB;
    for (int i = threadIdx.x; i < CLEN * 32; i += 256)
        bs[i] = xb[(i >> 5) * XDB + DTR + (i & 31)];
    __syncthreads();
    float an[NSTATE];
#pragma unroll
    for (int n4 = 0; n4 < 4; n4++) {
        float4 al = *(const float4*)(Alog + (size_t)d * NSTATE + n4 * 4);
        an[n4 * 4 + 0] = -__expf(al.x); an[n4 * 4 + 1] = -__expf(al.y);
        an[n4 * 4 + 2] = -__expf(al.z); an[n4 * 4 + 3] = -__expf(al.w);
    }
    float hs[NSTATE];
#pragma unroll
    for (int n = 0; n < NSTATE; n++) hs[n] = 0.f;
    // h_in(c) = sum_{j<c} exp(an * sum_{k in (j,c)} T_k) * h_fin(j)
    if (c > 0) {
        size_t hb = (size_t)(seq * CHUNK + (c - 1)) * NSTATE * DI + d;
#pragma unroll
        for (int n = 0; n < NSTATE; n++) hs[n] = b2f(hfin[hb + (size_t)n * DI]);
        float R = b2f(Tsum[(size_t)(seq * CHUNK + (c - 1)) * DI + d]);
        for (int j = c - 2; j >= 0; j--) {
            size_t hb2 = (size_t)(seq * CHUNK + j) * NSTATE * DI + d;
#pragma unroll
            for (int n = 0; n < NSTATE; n++)
                hs[n] += __expf(an[n] * R) * b2f(hfin[hb2 + (size_t)n * DI]);
            R += b2f(Tsum[(size_t)(seq * CHUNK + j) * DI + d]);
        }
    }
    float Dv = Dk[d];
    size_t base = ((size_t)seq * LSEQ + c * CLEN) * DI + d;
    for (int t = 0; t < CLEN; t++) {
        size_t off = base + (size_t)t * DI;
        float dt = delta[off];
        float uv = b2f(u[off]);
        float du = dt * uv;
        const float* Bp = bs + t * 32;
        float yv = 0.f;
#pragma unroll
        for (int n = 0; n < NSTATE; n++) {
            hs[n] = __expf(dt * an[n]) * hs[n] + du * Bp[n];
            yv += hs[n] * Bp[16 + n];
        }
        float v = yv + uv * Dv;
        float z = b2f(zb[off]);
        v *= z / (1.f + __expf(-z));
        yb[off] = f2b(v);
    }
}

// ---------- GEMM: C[M,N] = A[M,K](bf16) * B[N,K](bf16)^T ----------
// mode 0: f32 out (stride N)   mode 1: bf16 out (stride N)
// mode 2: split u/z (N=3072): col<DI -> f32 Cv (stride DI); col>=DI -> bf16 C2 (stride DI)
// mode 3: f32 out (stride N) AND col<DTR -> bf16 C2 (stride DTR)
__global__ __launch_bounds__(256, 2) void gemm_bt(const u16* __restrict__ A, const u16* __restrict__ B,
                                                  void* Cv, void* C2v, int M, int N, int K,
                                                  const float* __restrict__ bias, const float* resid,
                                                  int act, int mode) {
    __shared__ u16 lsa[128 * 64];
    __shared__ u16 lsb[128 * 64];
    const int t = threadIdx.x;
    const int bm = blockIdx.x, bn = blockIdx.y;
    const int lane = t & 63, w = t >> 6;
    const int wr = w >> 1, wc = w & 1;
    f32x4 zero4 = {0.f, 0.f, 0.f, 0.f};
    f32x4 acc[4][4];
#pragma unroll
    for (int i = 0; i < 4; i++)
#pragma unroll
        for (int j = 0; j < 4; j++) acc[i][j] = zero4;
    const int tr = t >> 3;  // 0..31
    const int tk = t & 7;   // 16B group (physical)
    const bool full = ((K & 63) == 0) && (bn * 128 + 128 <= N);
    const int arow = bm * 128, brow = bn * 128;

    for (int k0 = 0; k0 < K; k0 += 64) {
        if (full) {
#pragma unroll
            for (int p = 0; p < 4; ++p) {
                int row = p * 32 + tr;
                int klog = tk ^ (row & 7);
                const u16* ga = A + (size_t)(arow + row) * K + k0 + klog * 8;
                const u16* gb = B + (size_t)(brow + row) * K + k0 + klog * 8;
                __builtin_amdgcn_global_load_lds((const __attribute__((address_space(1))) void*)ga,
                                                 (__attribute__((address_space(3))) void*)((char*)lsa + p * 4096 + w * 1024),
                                                 16, 0, 0);
                __builtin_amdgcn_global_load_lds((const __attribute__((address_space(1))) void*)gb,
                                                 (__attribute__((address_space(3))) void*)((char*)lsb + p * 4096 + w * 1024),
                                                 16, 0, 0);
            }
        } else {
#pragma unroll
            for (int p = 0; p < 4; ++p) {
                int row = p * 32 + tr;
                int klog = tk ^ (row & 7);
                int kc = k0 + klog * 8;
                int4 va = {0, 0, 0, 0}, vb = {0, 0, 0, 0};
                if (kc < K) va = *(const int4*)(A + (size_t)(arow + row) * K + kc);
                if (kc < K && (brow + row) < N) vb = *(const int4*)(B + (size_t)(brow + row) * K + kc);
                *(int4*)((char*)lsa + row * 128 + tk * 16) = va;
                *(int4*)((char*)lsb + row * 128 + tk * 16) = vb;
            }
        }
        __syncthreads();
#pragma unroll
        for (int kc = 0; kc < 2; ++kc) {
            bf16x8 af[4], bfr[4];
            const int rr = lane & 15;
            const int g0 = kc * 4 + (lane >> 4);
            const int ph = (g0 ^ (rr & 7)) * 16;
#pragma unroll
            for (int i = 0; i < 4; ++i) {
                int row = wr * 64 + i * 16 + rr;
                af[i] = *(const bf16x8*)((const char*)lsa + row * 128 + ph);
            }
#pragma unroll
            for (int j = 0; j < 4; ++j) {
                int row = wc * 64 + j * 16 + rr;
                bfr[j] = *(const bf16x8*)((const char*)lsb + row * 128 + ph);
            }
#pragma unroll
            for (int i = 0; i < 4; ++i)
#pragma unroll
                for (int j = 0; j < 4; ++j)
                    acc[i][j] = __builtin_amdgcn_mfma_f32_16x16x32_bf16(af[i], bfr[j], acc[i][j], 0, 0, 0);
        }
        __syncthreads();
    }

    float* Cf = (float*)Cv;
    u16* Cb = (u16*)Cv;
    u16* C2 = (u16*)C2v;
    const int crow0 = bm * 128 + wr * 64;
    const int ccol0 = bn * 128 + wc * 64;
#pragma unroll
    for (int j = 0; j < 4; ++j) {
        int col = ccol0 + j * 16 + (lane & 15);
        if (col >= N) continue;
        float bv = bias ? bias[col] : 0.f;
#pragma unroll
        for (int i = 0; i < 4; ++i) {
#pragma unroll
            for (int r = 0; r < 4; ++r) {
                int row = crow0 + i * 16 + (lane >> 4) * 4 + r;
                float v = acc[i][j][r] + bv;
                if (resid) v += resid[(size_t)row * N + col];
                if (act == 1) v = softplusf(v);
                if (mode == 0) {
                    Cf[(size_t)row * N + col] = v;
                } else if (mode == 1) {
                    Cb[(size_t)row * N + col] = f2b(v);
                } else if (mode == 2) {
                    if (col < DI) Cf[(size_t)row * DI + col] = v;
                    else C2[(size_t)row * DI + (col - DI)] = f2b(v);
                } else {  // mode 3
                    Cf[(size_t)row * N + col] = v;
                    if (col < DTR) C2[(size_t)row * DTR + col] = f2b(v);
                }
            }
        }
    }
}

// ---------- weight offsets (u16 elements) ----------
#define WO_LIN_IN 0
#define WO_IN_PROJ 589824
#define WO_X_PROJ 5308416
#define WO_DT_PROJ 5554176
#define WO_OUT_PROJ 5701632
#define WO_LIN_OUT 8060928
// total wb elements: 8650752 -> 17301504 bytes

// ---------- workspace layout (bytes) ----------
#define O_WB    0
#define O_A0    17301504   // bf16 MROWS*DM (12582912 B) -- LN out, then hfin (64*4*1536*16*2 = exact fit)
#define O_H     29884416   // f32  MROWS*DM (25165824 B)
#define O_R1    55050240   // f32  MROWS*DI (50331648 B)  uraw / delta / yout
#define O_ZB    105381888  // bf16 MROWS*DI (25165824 B)
#define O_UB    130547712  // bf16 MROWS*DI (25165824 B)
#define O_XDBL  155713536  // f32  MROWS*XDB (2621440 B)
#define O_DTL   158334976  // bf16 MROWS*DTR (786432 B) -- dt_low, then Tsum (64*4*1536*2 = exact fit)
#define O_YB    159121408  // bf16 MROWS*DI (25165824 B)
#define WS_NEEDED 184287232ull

extern "C" void kernel_launch(void* const* d_in, const int* in_sizes, int n_in,
                              void* d_out, int out_size, void* d_ws, size_t ws_size,
                              hipStream_t stream) {
    const float* x        = (const float*)d_in[0];
    const float* lin_in_w = (const float*)d_in[1];
    const float* lin_in_b = (const float*)d_in[2];
    const float* lin_out_w = (const float*)d_in[3];
    const float* lin_out_b = (const float*)d_in[4];
    const float* norm_w   = (const float*)d_in[5];
    const float* norm_b   = (const float*)d_in[6];
    const float* in_proj_w = (const float*)d_in[7];
    const float* conv_w   = (const float*)d_in[8];
    const float* conv_b   = (const float*)d_in[9];
    const float* x_proj_w = (const float*)d_in[10];
    const float* dt_proj_w = (const float*)d_in[11];
    const float* dt_proj_b = (const float*)d_in[12];
    const float* A_log    = (const float*)d_in[13];
    const float* D_skip   = (const float*)d_in[14];
    const float* out_proj_w = (const float*)d_in[15];
    float* out = (float*)d_out;

    if (ws_size < WS_NEEDED) {
        diag_kernel<<<2048, 256, 0, stream>>>(out, out_size, (float)(ws_size >> 20));
        return;
    }

    char* ws = (char*)d_ws;
    u16* wb = (u16*)(ws + O_WB);
    u16* a0 = (u16*)(ws + O_A0);
    float* h = (float*)(ws + O_H);
    float* uraw = (float*)(ws + O_R1);
    float* delta = (float*)(ws + O_R1);
    float* yout = (float*)(ws + O_R1);
    u16* zb = (u16*)(ws + O_ZB);
    u16* ub = (u16*)(ws + O_UB);
    float* xdbl = (float*)(ws + O_XDBL);
    u16* dtl = (u16*)(ws + O_DTL);
    u16* hfin = (u16*)(ws + O_A0);    // alias a0 (dead at scan time)
    u16* tsum = (u16*)(ws + O_DTL);   // alias dtl (dead at scan time)
    u16* yb = (u16*)(ws + O_YB);

    auto cvt = [&](const float* s, u16* d, int n) {
        int g = (n + 255) / 256; if (g > 2048) g = 2048;
        cvt_kernel<<<g, 256, 0, stream>>>(s, d, n);
    };
    auto gemm = [&](const u16* Ap, const u16* Bp, void* Cp, void* C2p, int M_, int N_, int K_,
                    const float* bias, const float* resid, int act, int mode) {
        dim3 g(M_ / 128, (N_ + 127) / 128);
        gemm_bt<<<g, 256, 0, stream>>>(Ap, Bp, Cp, C2p, M_, N_, K_, bias, resid, act, mode);
    };

    // weights -> bf16
    cvt(lin_in_w, wb + WO_LIN_IN, 768 * 768);
    cvt(in_proj_w, wb + WO_IN_PROJ, 2 * 3072 * 768);
    cvt(x_proj_w, wb + WO_X_PROJ, 2 * 80 * 1536);
    cvt(dt_proj_w, wb + WO_DT_PROJ, 2 * 1536 * 48);
    cvt(out_proj_w, wb + WO_OUT_PROJ, 2 * 768 * 1536);
    cvt(lin_out_w, wb + WO_LIN_OUT, 768 * 768);

    // patchify + lin_in
    patchify_kernel<<<(MROWS * DM + 255) / 256, 256, 0, stream>>>(x, a0);
    gemm(a0, wb + WO_LIN_IN, h, nullptr, MROWS, DM, DM, lin_in_b, nullptr, 0, 0);

    for (int i = 0; i < 2; i++) {
        const u16* wip = wb + WO_IN_PROJ + (size_t)i * 2 * DI * DM;
        ln_kernel<<<MROWS, 256, 0, stream>>>(h, norm_w + i * DM, norm_b + i * DM, a0);
        // merged in_proj: u-half -> uraw (f32), z-half -> zb (bf16)
        gemm(a0, wip, uraw, zb, MROWS, 2 * DI, DM, nullptr, nullptr, 0, 2);
        conv_silu_kernel<<<(MROWS * DI + 255) / 256, 256, 0, stream>>>(uraw, conv_w + i * DI * 4, conv_b + i * DI, ub);
        // x_proj: xdbl (f32) + dt_low (bf16, cols<48)
        gemm(ub, wb + WO_X_PROJ + (size_t)i * XDB * DI, xdbl, dtl, MROWS, XDB, DI, nullptr, nullptr, 0, 3);
        gemm(dtl, wb + WO_DT_PROJ + (size_t)i * DI * DTR, delta, nullptr, MROWS, DI, DTR, dt_proj_b + i * DI, nullptr, 1, 0);
        scan1_kernel<<<dim3(DI / 256, SEQS, CHUNK), 256, 0, stream>>>(ub, delta, xdbl, A_log + i * DI * NSTATE, hfin, tsum);
        scan2_kernel<<<dim3(DI / 256, SEQS, CHUNK), 256, 0, stream>>>(ub, delta, xdbl, A_log + i * DI * NSTATE,
                                                                      hfin, tsum, zb, D_skip + i * DI, yb);
        gemm(yb, wb + WO_OUT_PROJ + (size_t)i * DM * DI, h, nullptr, MROWS, DM, DI, nullptr, h, 0, 0);
    }

    // lin_out + unpatchify
    cvt(h, a0, MROWS * DM);
    gemm(a0, wb + WO_LIN_OUT, yout, nullptr, MROWS, DM, DM, lin_out_b, nullptr, 0, 0);
    unpatchify_kernel<<<(MROWS * DM + 255) / 256, 256, 0, stream>>>(yout, out);
}

// Round 4
// 917.981 us; speedup vs baseline: 1.0448x; 1.0448x over previous
//
#include <hip/hip_runtime.h>

typedef unsigned short u16;
typedef __attribute__((ext_vector_type(8))) short bf16x8;
typedef __attribute__((ext_vector_type(4))) float f32x4;

#define SEQS 64
#define LSEQ 128
#define MROWS 8192
#define DM 768
#define DI 1536
#define NSTATE 16
#define DTR 48
#define XDB 80
#define CHUNK 4
#define CLEN 32  // LSEQ / CHUNK

// ---------- helpers ----------
__device__ __forceinline__ u16 f2b(float f) {
    unsigned int x = __builtin_bit_cast(unsigned int, f);
    unsigned int r = (x + 0x7fffu + ((x >> 16) & 1u)) >> 16;
    return (u16)r;
}
__device__ __forceinline__ float b2f(u16 v) {
    return __builtin_bit_cast(float, (unsigned int)v << 16);
}
__device__ __forceinline__ float softplusf(float x) {
    return x > 20.f ? x : log1pf(__expf(x));
}

// ---------- diagnostic ----------
__global__ void diag_kernel(float* __restrict__ out, int n, float v) {
    int i = blockIdx.x * 256 + threadIdx.x;
    int s = gridDim.x * 256;
    for (; i < n; i += s) out[i] = v;
}

// ---------- elementwise kernels ----------
__global__ void cvt_kernel(const float* __restrict__ src, u16* __restrict__ dst, int n) {
    int i = blockIdx.x * 256 + threadIdx.x;
    int stride = gridDim.x * 256;
    for (; i < n; i += stride) dst[i] = f2b(src[i]);
}

// pad K: dst[rows][kd], src[rows][ks], zeros for c >= ks
__global__ void cvt_pad_kernel(const float* __restrict__ src, u16* __restrict__ dst, int rows, int ks, int kd) {
    int idx = blockIdx.x * 256 + threadIdx.x;
    if (idx >= rows * kd) return;
    int r = idx / kd, c = idx - r * kd;
    dst[idx] = (c < ks) ? f2b(src[r * ks + c]) : (u16)0;
}

__global__ void patchify_kernel(const float* __restrict__ x, u16* __restrict__ o) {
    int idx = blockIdx.x * 256 + threadIdx.x;
    if (idx >= MROWS * DM) return;
    int col = idx % DM;
    int row = idx / DM;
    int t = row & 127, bb = row >> 7;
    int b = bb >> 4, h1 = (bb >> 2) & 3, h2 = bb & 3;
    int f = col >> 8, rem = col & 255, pi = rem >> 4, pj = rem & 15;
    size_t src = (size_t)(b * 128 + t) * 3 * 4096 + (size_t)f * 4096 + (h1 * 16 + pi) * 64 + h2 * 16 + pj;
    o[idx] = f2b(x[src]);
}

__global__ void unpatchify_kernel(const float* __restrict__ yo, float* __restrict__ out) {
    int idx = blockIdx.x * 256 + threadIdx.x;
    if (idx >= MROWS * DM) return;
    int w = idx & 63;
    int h = (idx >> 6) & 63;
    int f = (idx >> 12) % 3;
    int t = (idx / 12288) & 127;
    int b = idx / 1572864;
    int h1 = h >> 4, pi = h & 15, h2 = w >> 4, pj = w & 15;
    int row = ((b * 16 + h1 * 4 + h2) << 7) + t;
    int col = f * 256 + pi * 16 + pj;
    out[idx] = yo[(size_t)row * DM + col];
}

__global__ __launch_bounds__(256) void ln_kernel(const float* __restrict__ h, const float* __restrict__ w,
                                                 const float* __restrict__ b, u16* __restrict__ o) {
    __shared__ float red[8];
    int row = blockIdx.x, t = threadIdx.x;
    const float* hr = h + (size_t)row * DM;
    float v0 = hr[t], v1 = hr[t + 256], v2 = hr[t + 512];
    float s = v0 + v1 + v2;
    for (int off = 32; off; off >>= 1) s += __shfl_down(s, off);
    if ((t & 63) == 0) red[t >> 6] = s;
    __syncthreads();
    float mu = (red[0] + red[1] + red[2] + red[3]) * (1.f / 768.f);
    float d0 = v0 - mu, d1 = v1 - mu, d2 = v2 - mu;
    float q = d0 * d0 + d1 * d1 + d2 * d2;
    for (int off = 32; off; off >>= 1) q += __shfl_down(q, off);
    __syncthreads();
    if ((t & 63) == 0) red[4 + (t >> 6)] = q;
    __syncthreads();
    float var = (red[4] + red[5] + red[6] + red[7]) * (1.f / 768.f);
    float inv = rsqrtf(var + 1e-5f);
    u16* orow = o + (size_t)row * DM;
    orow[t]       = f2b(d0 * inv * w[t] + b[t]);
    orow[t + 256] = f2b(d1 * inv * w[t + 256] + b[t + 256]);
    orow[t + 512] = f2b(d2 * inv * w[t + 512] + b[t + 512]);
}

// causal depthwise conv (bf16 in) + SiLU -> bf16
__global__ void conv_silu_kernel(const u16* __restrict__ u0, const float* __restrict__ cw,
                                 const float* __restrict__ cb, u16* __restrict__ u) {
    int idx = blockIdx.x * 256 + threadIdx.x;
    if (idx >= MROWS * DI) return;
    int c = idx % DI;
    int r = idx / DI;
    int t = r & 127;
    const u16* base = u0 + (size_t)r * DI + c;
    float acc = cb[c];
#pragma unroll
    for (int k = 0; k < 4; k++) {
        int tt = t - 3 + k;
        if (tt >= 0) acc += b2f(base[(ptrdiff_t)(k - 3) * DI]) * cw[c * 4 + k];
    }
    float sv = acc / (1.f + __expf(-acc));
    u[idx] = f2b(sv);
}

// ---------- chunk-parallel selective scan ----------
// xbc layout: [row][32] f32: cols 0..15 = B, 16..31 = C
__global__ __launch_bounds__(256) void scan1_kernel(const u16* __restrict__ u, const float* __restrict__ delta,
                                                    const float* __restrict__ xbc, const float* __restrict__ Alog,
                                                    u16* __restrict__ hfin, u16* __restrict__ Tsum) {
    __shared__ float bs[CLEN * 16];
    int d = blockIdx.x * 256 + threadIdx.x;
    int seq = blockIdx.y, c = blockIdx.z;
    const float* xb = xbc + ((size_t)seq * LSEQ + c * CLEN) * 32;
    for (int i = threadIdx.x; i < CLEN * 16; i += 256)
        bs[i] = xb[(i >> 4) * 32 + (i & 15)];
    __syncthreads();
    float an[NSTATE];
#pragma unroll
    for (int n4 = 0; n4 < 4; n4++) {
        float4 al = *(const float4*)(Alog + (size_t)d * NSTATE + n4 * 4);
        an[n4 * 4 + 0] = -__expf(al.x); an[n4 * 4 + 1] = -__expf(al.y);
        an[n4 * 4 + 2] = -__expf(al.z); an[n4 * 4 + 3] = -__expf(al.w);
    }
    float hs[NSTATE];
#pragma unroll
    for (int n = 0; n < NSTATE; n++) hs[n] = 0.f;
    float S = 0.f;
    size_t base = ((size_t)seq * LSEQ + c * CLEN) * DI + d;
    for (int t = 0; t < CLEN; t++) {
        size_t off = base + (size_t)t * DI;
        float dt = delta[off];
        float uv = b2f(u[off]);
        S += dt;
        float du = dt * uv;
        const float* Bp = bs + t * 16;
#pragma unroll
        for (int n = 0; n < NSTATE; n++)
            hs[n] = __expf(dt * an[n]) * hs[n] + du * Bp[n];
    }
    size_t hb = (size_t)(seq * CHUNK + c) * NSTATE * DI + d;
#pragma unroll
    for (int n = 0; n < NSTATE; n++) hfin[hb + (size_t)n * DI] = f2b(hs[n]);
    Tsum[(size_t)(seq * CHUNK + c) * DI + d] = f2b(S);
}

__global__ __launch_bounds__(256) void scan2_kernel(const u16* __restrict__ u, const float* __restrict__ delta,
                                                    const float* __restrict__ xbc, const float* __restrict__ Alog,
                                                    const u16* __restrict__ hfin, const u16* __restrict__ Tsum,
                                                    const u16* __restrict__ zb, const float* __restrict__ Dk,
                                                    u16* __restrict__ yb) {
    __shared__ float bs[CLEN * 32];
    int d = blockIdx.x * 256 + threadIdx.x;
    int seq = blockIdx.y, c = blockIdx.z;
    const float* xb = xbc + ((size_t)seq * LSEQ + c * CLEN) * 32;
    for (int i = threadIdx.x; i < CLEN * 32; i += 256)
        bs[i] = xb[i];
    __syncthreads();
    float an[NSTATE];
#pragma unroll
    for (int n4 = 0; n4 < 4; n4++) {
        float4 al = *(const float4*)(Alog + (size_t)d * NSTATE + n4 * 4);
        an[n4 * 4 + 0] = -__expf(al.x); an[n4 * 4 + 1] = -__expf(al.y);
        an[n4 * 4 + 2] = -__expf(al.z); an[n4 * 4 + 3] = -__expf(al.w);
    }
    float hs[NSTATE];
#pragma unroll
    for (int n = 0; n < NSTATE; n++) hs[n] = 0.f;
    if (c > 0) {
        size_t hb = (size_t)(seq * CHUNK + (c - 1)) * NSTATE * DI + d;
#pragma unroll
        for (int n = 0; n < NSTATE; n++) hs[n] = b2f(hfin[hb + (size_t)n * DI]);
        float R = b2f(Tsum[(size_t)(seq * CHUNK + (c - 1)) * DI + d]);
        for (int j = c - 2; j >= 0; j--) {
            size_t hb2 = (size_t)(seq * CHUNK + j) * NSTATE * DI + d;
#pragma unroll
            for (int n = 0; n < NSTATE; n++)
                hs[n] += __expf(an[n] * R) * b2f(hfin[hb2 + (size_t)n * DI]);
            R += b2f(Tsum[(size_t)(seq * CHUNK + j) * DI + d]);
        }
    }
    float Dv = Dk[d];
    size_t base = ((size_t)seq * LSEQ + c * CLEN) * DI + d;
    for (int t = 0; t < CLEN; t++) {
        size_t off = base + (size_t)t * DI;
        float dt = delta[off];
        float uv = b2f(u[off]);
        float du = dt * uv;
        const float* Bp = bs + t * 32;
        float yv = 0.f;
#pragma unroll
        for (int n = 0; n < NSTATE; n++) {
            hs[n] = __expf(dt * an[n]) * hs[n] + du * Bp[n];
            yv += hs[n] * Bp[16 + n];
        }
        float v = yv + uv * Dv;
        float z = b2f(zb[off]);
        v *= z / (1.f + __expf(-z));
        yb[off] = f2b(v);
    }
}

// ---------- GEMM: C[M,N] = A[M,K](bf16) * B[N,K](bf16)^T ----------
// mode 0: f32 out, stride N (+bias, +resid, +softplus via act)
// mode 2: split in_proj: col<DI -> bf16 Cv (stride DI); col>=DI -> bf16 C2 (stride DI)
// mode 3: x_proj: col<48 -> bf16 C2 (stride 64, zeros for col 48..63); col>=48 -> f32 Cv (stride 32)
__global__ __launch_bounds__(256, 2) void gemm_bt(const u16* __restrict__ A, const u16* __restrict__ B,
                                                  void* Cv, void* C2v, int M, int N, int K,
                                                  const float* __restrict__ bias, const float* resid,
                                                  int act, int mode) {
    __shared__ u16 lsa[2][128 * 64];
    __shared__ u16 lsb[2][128 * 64];
    const int t = threadIdx.x;
    const int bm = blockIdx.x, bn = blockIdx.y;
    const int lane = t & 63, w = t >> 6;
    const int wr = w >> 1, wc = w & 1;
    f32x4 zero4 = {0.f, 0.f, 0.f, 0.f};
    f32x4 acc[4][4];
#pragma unroll
    for (int i = 0; i < 4; i++)
#pragma unroll
        for (int j = 0; j < 4; j++) acc[i][j] = zero4;
    const int tr = t >> 3;  // 0..31
    const int tk = t & 7;   // physical 16B slot
    const int arow = bm * 128, brow = bn * 128;
    const int Nm1 = N - 1;
    const bool full = ((K & 63) == 0);
    const int nt = K >> 6;

    if (full) {
        auto stage = [&](int buf, int kt) {
            int k0 = kt << 6;
#pragma unroll
            for (int p = 0; p < 4; ++p) {
                int row = p * 32 + tr;
                int klog = tk ^ (row & 7);
                const u16* ga = A + (size_t)(arow + row) * K + k0 + klog * 8;
                int rb = brow + row; rb = rb > Nm1 ? Nm1 : rb;  // clamp (junk cols masked at write)
                const u16* gb = B + (size_t)rb * K + k0 + klog * 8;
                __builtin_amdgcn_global_load_lds((const __attribute__((address_space(1))) void*)ga,
                    (__attribute__((address_space(3))) void*)((char*)lsa + buf * 16384 + p * 4096 + w * 1024), 16, 0, 0);
                __builtin_amdgcn_global_load_lds((const __attribute__((address_space(1))) void*)gb,
                    (__attribute__((address_space(3))) void*)((char*)lsb + buf * 16384 + p * 4096 + w * 1024), 16, 0, 0);
            }
        };
        stage(0, 0);
        for (int kt = 0; kt < nt; ++kt) {
            const int cur = kt & 1;
            if (kt + 1 < nt) {
                stage(cur ^ 1, kt + 1);
                __builtin_amdgcn_sched_barrier(0);
                asm volatile("s_waitcnt vmcnt(8)" ::: "memory");   // cur's 8 done; next 8 in flight
            } else {
                __builtin_amdgcn_sched_barrier(0);
                asm volatile("s_waitcnt vmcnt(0)" ::: "memory");
            }
            __builtin_amdgcn_s_barrier();
            __builtin_amdgcn_sched_barrier(0);
            const char* bA = (const char*)lsa + cur * 16384;
            const char* bB = (const char*)lsb + cur * 16384;
#pragma unroll
            for (int kc = 0; kc < 2; ++kc) {
                bf16x8 af[4], bfr[4];
                const int rr = lane & 15;
                const int g0 = kc * 4 + (lane >> 4);
                const int ph = (g0 ^ (rr & 7)) * 16;
#pragma unroll
                for (int i = 0; i < 4; ++i) {
                    int row = wr * 64 + i * 16 + rr;
                    af[i] = *(const bf16x8*)(bA + row * 128 + ph);
                }
#pragma unroll
                for (int j = 0; j < 4; ++j) {
                    int row = wc * 64 + j * 16 + rr;
                    bfr[j] = *(const bf16x8*)(bB + row * 128 + ph);
                }
#pragma unroll
                for (int i = 0; i < 4; ++i)
#pragma unroll
                    for (int j = 0; j < 4; ++j)
                        acc[i][j] = __builtin_amdgcn_mfma_f32_16x16x32_bf16(af[i], bfr[j], acc[i][j], 0, 0, 0);
            }
            __builtin_amdgcn_sched_barrier(0);
            __builtin_amdgcn_s_barrier();
        }
    } else {
        for (int k0 = 0; k0 < K; k0 += 64) {
#pragma unroll
            for (int p = 0; p < 4; ++p) {
                int row = p * 32 + tr;
                int klog = tk ^ (row & 7);
                int kc = k0 + klog * 8;
                int4 va = {0, 0, 0, 0}, vb = {0, 0, 0, 0};
                if (kc < K) va = *(const int4*)(A + (size_t)(arow + row) * K + kc);
                if (kc < K && (brow + row) < N) vb = *(const int4*)(B + (size_t)(brow + row) * K + kc);
                *(int4*)((char*)lsa[0] + row * 128 + tk * 16) = va;
                *(int4*)((char*)lsb[0] + row * 128 + tk * 16) = vb;
            }
            __syncthreads();
#pragma unroll
            for (int kc = 0; kc < 2; ++kc) {
                bf16x8 af[4], bfr[4];
                const int rr = lane & 15;
                const int g0 = kc * 4 + (lane >> 4);
                const int ph = (g0 ^ (rr & 7)) * 16;
#pragma unroll
                for (int i = 0; i < 4; ++i) {
                    int row = wr * 64 + i * 16 + rr;
                    af[i] = *(const bf16x8*)((const char*)lsa[0] + row * 128 + ph);
                }
#pragma unroll
                for (int j = 0; j < 4; ++j) {
                    int row = wc * 64 + j * 16 + rr;
                    bfr[j] = *(const bf16x8*)((const char*)lsb[0] + row * 128 + ph);
                }
#pragma unroll
                for (int i = 0; i < 4; ++i)
#pragma unroll
                    for (int j = 0; j < 4; ++j)
                        acc[i][j] = __builtin_amdgcn_mfma_f32_16x16x32_bf16(af[i], bfr[j], acc[i][j], 0, 0, 0);
            }
            __syncthreads();
        }
    }

    float* Cf = (float*)Cv;
    u16* Cb = (u16*)Cv;
    u16* C2 = (u16*)C2v;
    const int crow0 = bm * 128 + wr * 64;
    const int ccol0 = bn * 128 + wc * 64;
#pragma unroll
    for (int j = 0; j < 4; ++j) {
        int col = ccol0 + j * 16 + (lane & 15);
        if (col >= N) continue;
        float bv = bias ? bias[col] : 0.f;
#pragma unroll
        for (int i = 0; i < 4; ++i) {
#pragma unroll
            for (int r = 0; r < 4; ++r) {
                int row = crow0 + i * 16 + (lane >> 4) * 4 + r;
                float v = acc[i][j][r] + bv;
                if (resid) v += resid[(size_t)row * N + col];
                if (act == 1) v = softplusf(v);
                if (mode == 0) {
                    Cf[(size_t)row * N + col] = v;
                } else if (mode == 2) {
                    if (col < DI) Cb[(size_t)row * DI + col] = f2b(v);
                    else C2[(size_t)row * DI + (col - DI)] = f2b(v);
                } else {  // mode 3 (x_proj, N=80)
                    if (col < DTR) C2[(size_t)row * 64 + col] = f2b(v);
                    else {
                        if (col < 64) C2[(size_t)row * 64 + col] = 0;  // zero-pad dt_low cols 48..63
                        Cf[(size_t)row * 32 + (col - DTR)] = v;
                    }
                }
            }
        }
    }
}

// ---------- weight offsets (u16 elements) ----------
#define WO_LIN_IN 0
#define WO_IN_PROJ 589824
#define WO_X_PROJ 5308416
#define WO_DT_PROJ 5554176     // padded: 2 x 1536 x 64
#define WO_OUT_PROJ 5750784
#define WO_LIN_OUT 8110080
// total: 8699904 el = 17399808 B

// ---------- workspace layout (bytes) ----------
#define O_WB    0
#define O_A0    17399808   // bf16 MROWS*DM (12582912) -- LN out / hfin alias (exact fit)
#define O_H     29982720   // f32  MROWS*DM (25165824)
#define O_R1    55148544   // 50331648: u0 (bf16, first half) / delta (f32) / yout (f32)
#define O_ZB    105480192  // bf16 MROWS*DI (25165824)
#define O_UB    130646016  // bf16 MROWS*DI (25165824)
#define O_XBC   155811840  // f32  MROWS*32 (1048576)
#define O_DTL   156860416  // bf16 MROWS*64 (1048576) -- dt_low padded / Tsum alias
#define O_YB    157908992  // bf16 MROWS*DI (25165824)
#define WS_NEEDED 183074816ull

extern "C" void kernel_launch(void* const* d_in, const int* in_sizes, int n_in,
                              void* d_out, int out_size, void* d_ws, size_t ws_size,
                              hipStream_t stream) {
    const float* x        = (const float*)d_in[0];
    const float* lin_in_w = (const float*)d_in[1];
    const float* lin_in_b = (const float*)d_in[2];
    const float* lin_out_w = (const float*)d_in[3];
    const float* lin_out_b = (const float*)d_in[4];
    const float* norm_w   = (const float*)d_in[5];
    const float* norm_b   = (const float*)d_in[6];
    const float* in_proj_w = (const float*)d_in[7];
    const float* conv_w   = (const float*)d_in[8];
    const float* conv_b   = (const float*)d_in[9];
    const float* x_proj_w = (const float*)d_in[10];
    const float* dt_proj_w = (const float*)d_in[11];
    const float* dt_proj_b = (const float*)d_in[12];
    const float* A_log    = (const float*)d_in[13];
    const float* D_skip   = (const float*)d_in[14];
    const float* out_proj_w = (const float*)d_in[15];
    float* out = (float*)d_out;

    if (ws_size < WS_NEEDED) {
        diag_kernel<<<2048, 256, 0, stream>>>(out, out_size, (float)(ws_size >> 20));
        return;
    }

    char* ws = (char*)d_ws;
    u16* wb = (u16*)(ws + O_WB);
    u16* a0 = (u16*)(ws + O_A0);
    float* h = (float*)(ws + O_H);
    u16* u0 = (u16*)(ws + O_R1);
    float* delta = (float*)(ws + O_R1);
    float* yout = (float*)(ws + O_R1);
    u16* zb = (u16*)(ws + O_ZB);
    u16* ub = (u16*)(ws + O_UB);
    float* xbc = (float*)(ws + O_XBC);
    u16* dtl = (u16*)(ws + O_DTL);
    u16* hfin = (u16*)(ws + O_A0);
    u16* tsum = (u16*)(ws + O_DTL);
    u16* yb = (u16*)(ws + O_YB);

    auto cvt = [&](const float* s, u16* d, int n) {
        int g = (n + 255) / 256; if (g > 2048) g = 2048;
        cvt_kernel<<<g, 256, 0, stream>>>(s, d, n);
    };
    auto gemm = [&](const u16* Ap, const u16* Bp, void* Cp, void* C2p, int M_, int N_, int K_,
                    const float* bias, const float* resid, int act, int mode) {
        dim3 g(M_ / 128, (N_ + 127) / 128);
        gemm_bt<<<g, 256, 0, stream>>>(Ap, Bp, Cp, C2p, M_, N_, K_, bias, resid, act, mode);
    };

    // weights -> bf16 (dt_proj K-padded 48->64)
    cvt(lin_in_w, wb + WO_LIN_IN, 768 * 768);
    cvt(in_proj_w, wb + WO_IN_PROJ, 2 * 3072 * 768);
    cvt(x_proj_w, wb + WO_X_PROJ, 2 * 80 * 1536);
    cvt_pad_kernel<<<(2 * 1536 * 64 + 255) / 256, 256, 0, stream>>>(dt_proj_w, wb + WO_DT_PROJ, 2 * 1536, 48, 64);
    cvt(out_proj_w, wb + WO_OUT_PROJ, 2 * 768 * 1536);
    cvt(lin_out_w, wb + WO_LIN_OUT, 768 * 768);

    // patchify + lin_in
    patchify_kernel<<<(MROWS * DM + 255) / 256, 256, 0, stream>>>(x, a0);
    gemm(a0, wb + WO_LIN_IN, h, nullptr, MROWS, DM, DM, lin_in_b, nullptr, 0, 0);

    for (int i = 0; i < 2; i++) {
        const u16* wip = wb + WO_IN_PROJ + (size_t)i * 2 * DI * DM;
        ln_kernel<<<MROWS, 256, 0, stream>>>(h, norm_w + i * DM, norm_b + i * DM, a0);
        // in_proj: u-half -> u0 (bf16), z-half -> zb (bf16)
        gemm(a0, wip, u0, zb, MROWS, 2 * DI, DM, nullptr, nullptr, 0, 2);
        conv_silu_kernel<<<(MROWS * DI + 255) / 256, 256, 0, stream>>>(u0, conv_w + i * DI * 4, conv_b + i * DI, ub);
        // x_proj: B/C -> xbc (f32, stride 32), dt_low -> dtl (bf16, stride 64, zero-padded)
        gemm(ub, wb + WO_X_PROJ + (size_t)i * XDB * DI, xbc, dtl, MROWS, XDB, DI, nullptr, nullptr, 0, 3);
        // dt_proj (K padded to 64) + softplus -> delta f32 (overwrites dead u0)
        gemm(dtl, wb + WO_DT_PROJ + (size_t)i * DI * 64, delta, nullptr, MROWS, DI, 64, dt_proj_b + i * DI, nullptr, 1, 0);
        scan1_kernel<<<dim3(DI / 256, SEQS, CHUNK), 256, 0, stream>>>(ub, delta, xbc, A_log + i * DI * NSTATE, hfin, tsum);
        scan2_kernel<<<dim3(DI / 256, SEQS, CHUNK), 256, 0, stream>>>(ub, delta, xbc, A_log + i * DI * NSTATE,
                                                                      hfin, tsum, zb, D_skip + i * DI, yb);
        gemm(yb, wb + WO_OUT_PROJ + (size_t)i * DM * DI, h, nullptr, MROWS, DM, DI, nullptr, h, 0, 0);
    }

    // lin_out + unpatchify
    cvt(h, a0, MROWS * DM);
    gemm(a0, wb + WO_LIN_OUT, yout, nullptr, MROWS, DM, DM, lin_out_b, nullptr, 0, 0);
    unpatchify_kernel<<<(MROWS * DM + 255) / 256, 256, 0, stream>>>(yout, out);
}

// Round 5
// 849.618 us; speedup vs baseline: 1.1289x; 1.0805x over previous
//
#include <hip/hip_runtime.h>

typedef unsigned short u16;
typedef __attribute__((ext_vector_type(8))) short bf16x8;
typedef __attribute__((ext_vector_type(4))) float f32x4;

#define SEQS 64
#define LSEQ 128
#define MROWS 8192
#define DM 768
#define DI 1536
#define NSTATE 16
#define DTR 48
#define XDB 80
#define CHUNK 4
#define CLEN 32  // LSEQ / CHUNK

// ---------- helpers ----------
__device__ __forceinline__ u16 f2b(float f) {
    unsigned int x = __builtin_bit_cast(unsigned int, f);
    unsigned int r = (x + 0x7fffu + ((x >> 16) & 1u)) >> 16;
    return (u16)r;
}
__device__ __forceinline__ float b2f(u16 v) {
    return __builtin_bit_cast(float, (unsigned int)v << 16);
}
__device__ __forceinline__ float softplusf(float x) {
    return x > 20.f ? x : log1pf(__expf(x));
}

// ---------- diagnostic ----------
__global__ void diag_kernel(float* __restrict__ out, int n, float v) {
    int i = blockIdx.x * 256 + threadIdx.x;
    int s = gridDim.x * 256;
    for (; i < n; i += s) out[i] = v;
}

// ---------- elementwise kernels ----------
__global__ void cvt_kernel(const float* __restrict__ src, u16* __restrict__ dst, int n) {
    int i = blockIdx.x * 256 + threadIdx.x;
    int stride = gridDim.x * 256;
    for (; i < n; i += stride) dst[i] = f2b(src[i]);
}

__global__ void cvt_pad_kernel(const float* __restrict__ src, u16* __restrict__ dst, int rows, int ks, int kd) {
    int idx = blockIdx.x * 256 + threadIdx.x;
    if (idx >= rows * kd) return;
    int r = idx / kd, c = idx - r * kd;
    dst[idx] = (c < ks) ? f2b(src[r * ks + c]) : (u16)0;
}

__global__ void patchify_kernel(const float* __restrict__ x, u16* __restrict__ o) {
    int idx = blockIdx.x * 256 + threadIdx.x;
    if (idx >= MROWS * DM) return;
    int col = idx % DM;
    int row = idx / DM;
    int t = row & 127, bb = row >> 7;
    int b = bb >> 4, h1 = (bb >> 2) & 3, h2 = bb & 3;
    int f = col >> 8, rem = col & 255, pi = rem >> 4, pj = rem & 15;
    size_t src = (size_t)(b * 128 + t) * 3 * 4096 + (size_t)f * 4096 + (h1 * 16 + pi) * 64 + h2 * 16 + pj;
    o[idx] = f2b(x[src]);
}

__global__ void unpatchify_kernel(const float* __restrict__ yo, float* __restrict__ out) {
    int idx = blockIdx.x * 256 + threadIdx.x;
    if (idx >= MROWS * DM) return;
    int w = idx & 63;
    int h = (idx >> 6) & 63;
    int f = (idx >> 12) % 3;
    int t = (idx / 12288) & 127;
    int b = idx / 1572864;
    int h1 = h >> 4, pi = h & 15, h2 = w >> 4, pj = w & 15;
    int row = ((b * 16 + h1 * 4 + h2) << 7) + t;
    int col = f * 256 + pi * 16 + pj;
    out[idx] = yo[(size_t)row * DM + col];
}

__global__ __launch_bounds__(256) void ln_kernel(const float* __restrict__ h, const float* __restrict__ w,
                                                 const float* __restrict__ b, u16* __restrict__ o) {
    __shared__ float red[8];
    int row = blockIdx.x, t = threadIdx.x;
    const float* hr = h + (size_t)row * DM;
    float v0 = hr[t], v1 = hr[t + 256], v2 = hr[t + 512];
    float s = v0 + v1 + v2;
    for (int off = 32; off; off >>= 1) s += __shfl_down(s, off);
    if ((t & 63) == 0) red[t >> 6] = s;
    __syncthreads();
    float mu = (red[0] + red[1] + red[2] + red[3]) * (1.f / 768.f);
    float d0 = v0 - mu, d1 = v1 - mu, d2 = v2 - mu;
    float q = d0 * d0 + d1 * d1 + d2 * d2;
    for (int off = 32; off; off >>= 1) q += __shfl_down(q, off);
    __syncthreads();
    if ((t & 63) == 0) red[4 + (t >> 6)] = q;
    __syncthreads();
    float var = (red[4] + red[5] + red[6] + red[7]) * (1.f / 768.f);
    float inv = rsqrtf(var + 1e-5f);
    u16* orow = o + (size_t)row * DM;
    orow[t]       = f2b(d0 * inv * w[t] + b[t]);
    orow[t + 256] = f2b(d1 * inv * w[t + 256] + b[t + 256]);
    orow[t + 512] = f2b(d2 * inv * w[t + 512] + b[t + 512]);
}

// causal depthwise conv (bf16 in) + SiLU -> bf16
__global__ void conv_silu_kernel(const u16* __restrict__ u0, const float* __restrict__ cw,
                                 const float* __restrict__ cb, u16* __restrict__ u) {
    int idx = blockIdx.x * 256 + threadIdx.x;
    if (idx >= MROWS * DI) return;
    int c = idx % DI;
    int r = idx / DI;
    int t = r & 127;
    const u16* base = u0 + (size_t)r * DI + c;
    float acc = cb[c];
#pragma unroll
    for (int k = 0; k < 4; k++) {
        int tt = t - 3 + k;
        if (tt >= 0) acc += b2f(base[(ptrdiff_t)(k - 3) * DI]) * cw[c * 4 + k];
    }
    float sv = acc / (1.f + __expf(-acc));
    u[idx] = f2b(sv);
}

// ---------- chunk-parallel selective scan ----------
// xbc layout: [row][32] f32: cols 0..15 = B, 16..31 = C
__global__ __launch_bounds__(256) void scan1_kernel(const u16* __restrict__ u, const float* __restrict__ delta,
                                                    const float* __restrict__ xbc, const float* __restrict__ Alog,
                                                    u16* __restrict__ hfin, u16* __restrict__ Tsum) {
    __shared__ float bs[CLEN * 16];
    int d = blockIdx.x * 256 + threadIdx.x;
    int seq = blockIdx.y, c = blockIdx.z;
    const float* xb = xbc + ((size_t)seq * LSEQ + c * CLEN) * 32;
    for (int i = threadIdx.x; i < CLEN * 16; i += 256)
        bs[i] = xb[(i >> 4) * 32 + (i & 15)];
    __syncthreads();
    float an[NSTATE];
#pragma unroll
    for (int n4 = 0; n4 < 4; n4++) {
        float4 al = *(const float4*)(Alog + (size_t)d * NSTATE + n4 * 4);
        an[n4 * 4 + 0] = -__expf(al.x); an[n4 * 4 + 1] = -__expf(al.y);
        an[n4 * 4 + 2] = -__expf(al.z); an[n4 * 4 + 3] = -__expf(al.w);
    }
    float hs[NSTATE];
#pragma unroll
    for (int n = 0; n < NSTATE; n++) hs[n] = 0.f;
    float S = 0.f;
    size_t base = ((size_t)seq * LSEQ + c * CLEN) * DI + d;
    for (int t = 0; t < CLEN; t++) {
        size_t off = base + (size_t)t * DI;
        float dt = delta[off];
        float uv = b2f(u[off]);
        S += dt;
        float du = dt * uv;
        const float* Bp = bs + t * 16;
#pragma unroll
        for (int n = 0; n < NSTATE; n++)
            hs[n] = __expf(dt * an[n]) * hs[n] + du * Bp[n];
    }
    size_t hb = (size_t)(seq * CHUNK + c) * NSTATE * DI + d;
#pragma unroll
    for (int n = 0; n < NSTATE; n++) hfin[hb + (size_t)n * DI] = f2b(hs[n]);
    Tsum[(size_t)(seq * CHUNK + c) * DI + d] = f2b(S);
}

__global__ __launch_bounds__(256) void scan2_kernel(const u16* __restrict__ u, const float* __restrict__ delta,
                                                    const float* __restrict__ xbc, const float* __restrict__ Alog,
                                                    const u16* __restrict__ hfin, const u16* __restrict__ Tsum,
                                                    const u16* __restrict__ zb, const float* __restrict__ Dk,
                                                    u16* __restrict__ yb) {
    __shared__ float bs[CLEN * 32];
    int d = blockIdx.x * 256 + threadIdx.x;
    int seq = blockIdx.y, c = blockIdx.z;
    const float* xb = xbc + ((size_t)seq * LSEQ + c * CLEN) * 32;
    for (int i = threadIdx.x; i < CLEN * 32; i += 256)
        bs[i] = xb[i];
    __syncthreads();
    float an[NSTATE];
#pragma unroll
    for (int n4 = 0; n4 < 4; n4++) {
        float4 al = *(const float4*)(Alog + (size_t)d * NSTATE + n4 * 4);
        an[n4 * 4 + 0] = -__expf(al.x); an[n4 * 4 + 1] = -__expf(al.y);
        an[n4 * 4 + 2] = -__expf(al.z); an[n4 * 4 + 3] = -__expf(al.w);
    }
    float hs[NSTATE];
#pragma unroll
    for (int n = 0; n < NSTATE; n++) hs[n] = 0.f;
    if (c > 0) {
        size_t hb = (size_t)(seq * CHUNK + (c - 1)) * NSTATE * DI + d;
#pragma unroll
        for (int n = 0; n < NSTATE; n++) hs[n] = b2f(hfin[hb + (size_t)n * DI]);
        float R = b2f(Tsum[(size_t)(seq * CHUNK + (c - 1)) * DI + d]);
        for (int j = c - 2; j >= 0; j--) {
            size_t hb2 = (size_t)(seq * CHUNK + j) * NSTATE * DI + d;
#pragma unroll
            for (int n = 0; n < NSTATE; n++)
                hs[n] += __expf(an[n] * R) * b2f(hfin[hb2 + (size_t)n * DI]);
            R += b2f(Tsum[(size_t)(seq * CHUNK + j) * DI + d]);
        }
    }
    float Dv = Dk[d];
    size_t base = ((size_t)seq * LSEQ + c * CLEN) * DI + d;
    for (int t = 0; t < CLEN; t++) {
        size_t off = base + (size_t)t * DI;
        float dt = delta[off];
        float uv = b2f(u[off]);
        float du = dt * uv;
        const float* Bp = bs + t * 32;
        float yv = 0.f;
#pragma unroll
        for (int n = 0; n < NSTATE; n++) {
            hs[n] = __expf(dt * an[n]) * hs[n] + du * Bp[n];
            yv += hs[n] * Bp[16 + n];
        }
        float v = yv + uv * Dv;
        float z = b2f(zb[off]);
        v *= z / (1.f + __expf(-z));
        yb[off] = f2b(v);
    }
}

// ---------- GEMM: C[M,N] = A[M,K](bf16) * B[N,K](bf16)^T,  K % 64 == 0 ----------
// mode 0: f32 out, stride N (+bias, +resid, +softplus via act)
// mode 2: split in_proj: col<DI -> bf16 Cv (stride DI); col>=DI -> bf16 C2 (stride DI)
// mode 3: x_proj: col<48 -> bf16 C2 (stride 64, zeros for col 48..63); col>=48 -> f32 Cv (stride 32)
__global__ __launch_bounds__(256) void gemm_bt(const u16* __restrict__ A, const u16* __restrict__ B,
                                               void* Cv, void* C2v, int M, int N, int K,
                                               const float* __restrict__ bias, const float* resid,
                                               int act, int mode) {
    __shared__ u16 lsa[2][128 * 64];
    __shared__ u16 lsb[2][128 * 64];
    const int t = threadIdx.x;
    const int bm = blockIdx.x, bn = blockIdx.y;
    const int lane = t & 63, w = t >> 6;
    const int wr = w >> 1, wc = w & 1;
    f32x4 zero4 = {0.f, 0.f, 0.f, 0.f};
    f32x4 acc[4][4];
#pragma unroll
    for (int i = 0; i < 4; i++)
#pragma unroll
        for (int j = 0; j < 4; j++) acc[i][j] = zero4;
    const int tr = t >> 3;  // 0..31
    const int tk = t & 7;   // physical 16B slot
    const int arow0 = bm * 128, brow0 = bn * 128;
    const int Nm1 = N - 1;
    const int nt = K >> 6;

    auto stage = [&](int buf, int kt) {
        int k0 = kt << 6;
#pragma unroll
        for (int p = 0; p < 4; ++p) {
            int row = p * 32 + tr;
            int klog = tk ^ (row & 7);
            const u16* ga = A + (size_t)(arow0 + row) * K + k0 + klog * 8;
            int rb = brow0 + row; rb = rb > Nm1 ? Nm1 : rb;  // clamp (junk cols masked at write)
            const u16* gb = B + (size_t)rb * K + k0 + klog * 8;
            __builtin_amdgcn_global_load_lds((const __attribute__((address_space(1))) void*)ga,
                (__attribute__((address_space(3))) void*)((char*)lsa + buf * 16384 + p * 4096 + w * 1024), 16, 0, 0);
            __builtin_amdgcn_global_load_lds((const __attribute__((address_space(1))) void*)gb,
                (__attribute__((address_space(3))) void*)((char*)lsb + buf * 16384 + p * 4096 + w * 1024), 16, 0, 0);
        }
    };

    // per-thread fragment LDS byte addresses (low 32 bits of generic addr = LDS offset)
    const unsigned abase = (unsigned)(unsigned long long)(&lsa[0][0]);
    const unsigned bbase = (unsigned)(unsigned long long)(&lsb[0][0]);
    const int rr = lane & 15;
    const int hi = lane >> 4;
    const int s3 = rr & 7;
    const unsigned ph0 = (unsigned)(((0 + hi) ^ s3) * 16);
    const unsigned ph1 = (unsigned)(((4 + hi) ^ s3) * 16);
    unsigned arow[4], browb[4];
#pragma unroll
    for (int i = 0; i < 4; ++i) arow[i] = (unsigned)((wr * 64 + i * 16 + rr) * 128);
#pragma unroll
    for (int j = 0; j < 4; ++j) browb[j] = (unsigned)((wc * 64 + j * 16 + rr) * 128);

    stage(0, 0);
    for (int kt = 0; kt < nt; ++kt) {
        const int cur = kt & 1;
        if (kt + 1 < nt) {
            stage(cur ^ 1, kt + 1);
            asm volatile("s_waitcnt vmcnt(8)" ::: "memory");   // cur's 8 landed; next 8 stay in flight
        } else {
            asm volatile("s_waitcnt vmcnt(0)" ::: "memory");
        }
        __builtin_amdgcn_s_barrier();
        __builtin_amdgcn_sched_barrier(0);
        const unsigned ab = abase + (unsigned)(cur * 16384);
        const unsigned bb = bbase + (unsigned)(cur * 16384);
        bf16x8 af0[4], bg0[4], af1[4], bg1[4];
#pragma unroll
        for (int i = 0; i < 4; ++i)
            asm volatile("ds_read_b128 %0, %1" : "=v"(af0[i]) : "v"(ab + arow[i] + ph0));
#pragma unroll
        for (int j = 0; j < 4; ++j)
            asm volatile("ds_read_b128 %0, %1" : "=v"(bg0[j]) : "v"(bb + browb[j] + ph0));
#pragma unroll
        for (int i = 0; i < 4; ++i)
            asm volatile("ds_read_b128 %0, %1" : "=v"(af1[i]) : "v"(ab + arow[i] + ph1));
#pragma unroll
        for (int j = 0; j < 4; ++j)
            asm volatile("ds_read_b128 %0, %1" : "=v"(bg1[j]) : "v"(bb + browb[j] + ph1));
        asm volatile("s_waitcnt lgkmcnt(8)" ::: "memory");
        __builtin_amdgcn_sched_barrier(0);
#pragma unroll
        for (int i = 0; i < 4; ++i)
#pragma unroll
            for (int j = 0; j < 4; ++j)
                acc[i][j] = __builtin_amdgcn_mfma_f32_16x16x32_bf16(af0[i], bg0[j], acc[i][j], 0, 0, 0);
        asm volatile("s_waitcnt lgkmcnt(0)" ::: "memory");
        __builtin_amdgcn_sched_barrier(0);
#pragma unroll
        for (int i = 0; i < 4; ++i)
#pragma unroll
            for (int j = 0; j < 4; ++j)
                acc[i][j] = __builtin_amdgcn_mfma_f32_16x16x32_bf16(af1[i], bg1[j], acc[i][j], 0, 0, 0);
        __builtin_amdgcn_sched_barrier(0);
        __builtin_amdgcn_s_barrier();
    }

    float* Cf = (float*)Cv;
    u16* Cb = (u16*)Cv;
    u16* C2 = (u16*)C2v;
    const int crow0 = bm * 128 + wr * 64;
    const int ccol0 = bn * 128 + wc * 64;
#pragma unroll
    for (int j = 0; j < 4; ++j) {
        int col = ccol0 + j * 16 + (lane & 15);
        if (col >= N) continue;
        float bv = bias ? bias[col] : 0.f;
#pragma unroll
        for (int i = 0; i < 4; ++i) {
#pragma unroll
            for (int r = 0; r < 4; ++r) {
                int row = crow0 + i * 16 + (lane >> 4) * 4 + r;
                float v = acc[i][j][r] + bv;
                if (resid) v += resid[(size_t)row * N + col];
                if (act == 1) v = softplusf(v);
                if (mode == 0) {
                    Cf[(size_t)row * N + col] = v;
                } else if (mode == 2) {
                    if (col < DI) Cb[(size_t)row * DI + col] = f2b(v);
                    else C2[(size_t)row * DI + (col - DI)] = f2b(v);
                } else {  // mode 3 (x_proj, N=80)
                    if (col < DTR) C2[(size_t)row * 64 + col] = f2b(v);
                    else {
                        if (col < 64) C2[(size_t)row * 64 + col] = 0;  // zero-pad dt_low cols 48..63
                        Cf[(size_t)row * 32 + (col - DTR)] = v;
                    }
                }
            }
        }
    }
}

// ---------- weight offsets (u16 elements) ----------
#define WO_LIN_IN 0
#define WO_IN_PROJ 589824
#define WO_X_PROJ 5308416
#define WO_DT_PROJ 5554176     // padded: 2 x 1536 x 64
#define WO_OUT_PROJ 5750784
#define WO_LIN_OUT 8110080
// total: 8699904 el = 17399808 B

// ---------- workspace layout (bytes) ----------
#define O_WB    0
#define O_A0    17399808   // bf16 MROWS*DM (12582912) -- LN out / hfin alias (exact fit)
#define O_H     29982720   // f32  MROWS*DM (25165824)
#define O_R1    55148544   // 50331648: u0 (bf16, first half) / delta (f32) / yout (f32)
#define O_ZB    105480192  // bf16 MROWS*DI (25165824)
#define O_UB    130646016  // bf16 MROWS*DI (25165824)
#define O_XBC   155811840  // f32  MROWS*32 (1048576)
#define O_DTL   156860416  // bf16 MROWS*64 (1048576) -- dt_low padded / Tsum alias
#define O_YB    157908992  // bf16 MROWS*DI (25165824)
#define WS_NEEDED 183074816ull

extern "C" void kernel_launch(void* const* d_in, const int* in_sizes, int n_in,
                              void* d_out, int out_size, void* d_ws, size_t ws_size,
                              hipStream_t stream) {
    const float* x        = (const float*)d_in[0];
    const float* lin_in_w = (const float*)d_in[1];
    const float* lin_in_b = (const float*)d_in[2];
    const float* lin_out_w = (const float*)d_in[3];
    const float* lin_out_b = (const float*)d_in[4];
    const float* norm_w   = (const float*)d_in[5];
    const float* norm_b   = (const float*)d_in[6];
    const float* in_proj_w = (const float*)d_in[7];
    const float* conv_w   = (const float*)d_in[8];
    const float* conv_b   = (const float*)d_in[9];
    const float* x_proj_w = (const float*)d_in[10];
    const float* dt_proj_w = (const float*)d_in[11];
    const float* dt_proj_b = (const float*)d_in[12];
    const float* A_log    = (const float*)d_in[13];
    const float* D_skip   = (const float*)d_in[14];
    const float* out_proj_w = (const float*)d_in[15];
    float* out = (float*)d_out;

    if (ws_size < WS_NEEDED) {
        diag_kernel<<<2048, 256, 0, stream>>>(out, out_size, (float)(ws_size >> 20));
        return;
    }

    char* ws = (char*)d_ws;
    u16* wb = (u16*)(ws + O_WB);
    u16* a0 = (u16*)(ws + O_A0);
    float* h = (float*)(ws + O_H);
    u16* u0 = (u16*)(ws + O_R1);
    float* delta = (float*)(ws + O_R1);
    float* yout = (float*)(ws + O_R1);
    u16* zb = (u16*)(ws + O_ZB);
    u16* ub = (u16*)(ws + O_UB);
    float* xbc = (float*)(ws + O_XBC);
    u16* dtl = (u16*)(ws + O_DTL);
    u16* hfin = (u16*)(ws + O_A0);
    u16* tsum = (u16*)(ws + O_DTL);
    u16* yb = (u16*)(ws + O_YB);

    auto cvt = [&](const float* s, u16* d, int n) {
        int g = (n + 255) / 256; if (g > 2048) g = 2048;
        cvt_kernel<<<g, 256, 0, stream>>>(s, d, n);
    };
    auto gemm = [&](const u16* Ap, const u16* Bp, void* Cp, void* C2p, int M_, int N_, int K_,
                    const float* bias, const float* resid, int act, int mode) {
        dim3 g(M_ / 128, (N_ + 127) / 128);
        gemm_bt<<<g, 256, 0, stream>>>(Ap, Bp, Cp, C2p, M_, N_, K_, bias, resid, act, mode);
    };

    // weights -> bf16 (dt_proj K-padded 48->64)
    cvt(lin_in_w, wb + WO_LIN_IN, 768 * 768);
    cvt(in_proj_w, wb + WO_IN_PROJ, 2 * 3072 * 768);
    cvt(x_proj_w, wb + WO_X_PROJ, 2 * 80 * 1536);
    cvt_pad_kernel<<<(2 * 1536 * 64 + 255) / 256, 256, 0, stream>>>(dt_proj_w, wb + WO_DT_PROJ, 2 * 1536, 48, 64);
    cvt(out_proj_w, wb + WO_OUT_PROJ, 2 * 768 * 1536);
    cvt(lin_out_w, wb + WO_LIN_OUT, 768 * 768);

    // patchify + lin_in
    patchify_kernel<<<(MROWS * DM + 255) / 256, 256, 0, stream>>>(x, a0);
    gemm(a0, wb + WO_LIN_IN, h, nullptr, MROWS, DM, DM, lin_in_b, nullptr, 0, 0);

    for (int i = 0; i < 2; i++) {
        const u16* wip = wb + WO_IN_PROJ + (size_t)i * 2 * DI * DM;
        ln_kernel<<<MROWS, 256, 0, stream>>>(h, norm_w + i * DM, norm_b + i * DM, a0);
        // in_proj: u-half -> u0 (bf16), z-half -> zb (bf16)
        gemm(a0, wip, u0, zb, MROWS, 2 * DI, DM, nullptr, nullptr, 0, 2);
        conv_silu_kernel<<<(MROWS * DI + 255) / 256, 256, 0, stream>>>(u0, conv_w + i * DI * 4, conv_b + i * DI, ub);
        // x_proj: B/C -> xbc (f32, stride 32), dt_low -> dtl (bf16, stride 64, zero-padded)
        gemm(ub, wb + WO_X_PROJ + (size_t)i * XDB * DI, xbc, dtl, MROWS, XDB, DI, nullptr, nullptr, 0, 3);
        // dt_proj (K padded to 64) + softplus -> delta f32 (overwrites dead u0)
        gemm(dtl, wb + WO_DT_PROJ + (size_t)i * DI * 64, delta, nullptr, MROWS, DI, 64, dt_proj_b + i * DI, nullptr, 1, 0);
        scan1_kernel<<<dim3(DI / 256, SEQS, CHUNK), 256, 0, stream>>>(ub, delta, xbc, A_log + i * DI * NSTATE, hfin, tsum);
        scan2_kernel<<<dim3(DI / 256, SEQS, CHUNK), 256, 0, stream>>>(ub, delta, xbc, A_log + i * DI * NSTATE,
                                                                      hfin, tsum, zb, D_skip + i * DI, yb);
        gemm(yb, wb + WO_OUT_PROJ + (size_t)i * DM * DI, h, nullptr, MROWS, DM, DI, nullptr, h, 0, 0);
    }

    // lin_out + unpatchify
    cvt(h, a0, MROWS * DM);
    gemm(a0, wb + WO_LIN_OUT, yout, nullptr, MROWS, DM, DM, lin_out_b, nullptr, 0, 0);
    unpatchify_kernel<<<(MROWS * DM + 255) / 256, 256, 0, stream>>>(yout, out);
}